// Round 1
// baseline (591.737 us; speedup 1.0000x reference)
//
#include <hip/hip_runtime.h>

#define AS1 __attribute__((address_space(1)))
#define AS3 __attribute__((address_space(3)))

using u16 = unsigned short;
using u32 = unsigned int;
typedef __attribute__((ext_vector_type(8))) short bf16x8;
typedef __attribute__((ext_vector_type(4))) float f32x4;

constexpr int Bn    = 32;
constexpr int Tn    = 16384;
constexpr int TCn   = 16364;   // Tn - (K-1)
constexpr int TILE  = 256;     // conv block t-tile (64 tiles exactly)
constexpr int XROWS = 280;     // staged rows per conv block
constexpr int TPAD  = 16416;   // Tn + 32 zero pad rows

__device__ __forceinline__ u16 f2bf(float f) {
  union { float f; u32 u; } v; v.f = f;
  u32 u = v.u;
  u += 0x7fffu + ((u >> 16) & 1u);   // RNE
  return (u16)(u >> 16);
}
__device__ __forceinline__ float bf2f(u32 h) {
  union { u32 u; float f; } v; v.u = h << 16; return v.f;
}
// order-preserving float<->uint for atomicMax on signed floats
__device__ __forceinline__ u32 encf(float f) {
  union { float f; u32 u; } v; v.f = f;
  return (v.u & 0x80000000u) ? ~v.u : (v.u | 0x80000000u);
}
__device__ __forceinline__ float decf(u32 u) {
  union { u32 u; float f; } v;
  v.u = (u & 0x80000000u) ? (u ^ 0x80000000u) : ~u;
  return v.f;
}
__device__ __forceinline__ void gload_lds16(const void* g, void* l) {
  __builtin_amdgcn_global_load_lds((const AS1 u32*)g, (AS3 u32*)l, 16, 0, 0);
}
__device__ __forceinline__ float leaky(float z) { return z > 0.f ? z : 0.01f * z; }

// ---------------------------------------------------------------------------
// Kernel 1: (a) x -> x_t[b][t][ci ^ ((t&7)*8)] bf16 + zero pad (b64 LDS writes,
// swizzle applied on LDS read — verified correct);
// (b) tail blocks repack weights into MFMA A-fragment order.
// UNCHANGED from measured round (near BW bound).
// ---------------------------------------------------------------------------
__global__ __launch_bounds__(256) void transpose_x(const float* __restrict__ x,
                                                   u16* __restrict__ x_t,
                                                   const float* __restrict__ w1,
                                                   const float* __restrict__ w2,
                                                   u16* __restrict__ wf1,
                                                   u16* __restrict__ wf2) {
  __shared__ u16 lt[64][64];               // 8 KB, [t][ci] (plain)
  const int bx  = blockIdx.x;
  const int tid = threadIdx.x;

  if (bx >= Bn * 256) {                    // ---- weight repack (84 blocks) ----
    const int bxx = bx - Bn * 256;
    const int cv  = bxx / 42;
    const int c   = bxx % 42;
    const float* w = cv ? w2 : w1;
    u16* wf = cv ? wf2 : wf1;
    const int ct   = tid >> 6;
    const int lane = tid & 63;
    const int q  = lane >> 4;
    const int rr = lane & 15;
    const int k  = c >> 1;
    const int cb = (c & 1) * 32;
    const int co = ct * 16 + rr;
    u16 us[8] __attribute__((aligned(16)));
#pragma unroll
    for (int j = 0; j < 8; ++j) {
      int ci = cb + q * 8 + j;
      us[j] = f2bf(w[((size_t)co * 64 + ci) * 21 + k]);
    }
    *(uint4*)&wf[((size_t)(c * 4 + ct) * 64 + lane) * 8] = *(const uint4*)us;
    return;
  }

  const int b   = bx >> 8;
  const int tt  = bx & 255;
  const int t0  = tt * 64;
  const int ci0 = (tid & 15) * 4;
  const int tl0 = (tid >> 4) * 4;
  float4 v[4];
#pragma unroll
  for (int j = 0; j < 4; ++j)
    v[j] = *(const float4*)(x + (size_t)(b * 64 + ci0 + j) * Tn + t0 + tl0);
  float vr[4][4] = {{v[0].x,v[0].y,v[0].z,v[0].w},{v[1].x,v[1].y,v[1].z,v[1].w},
                    {v[2].x,v[2].y,v[2].z,v[2].w},{v[3].x,v[3].y,v[3].z,v[3].w}};
#pragma unroll
  for (int e = 0; e < 4; ++e) {
    int tl = tl0 + e;
    u32 lo = (u32)f2bf(vr[0][e]) | ((u32)f2bf(vr[1][e]) << 16);
    u32 hi = (u32)f2bf(vr[2][e]) | ((u32)f2bf(vr[3][e]) << 16);
    uint2 pk = make_uint2(lo, hi);
    *(uint2*)&lt[tl][ci0] = pk;              // ds_write_b64, PLAIN index
  }
  __syncthreads();
  const int row = tid >> 2;
  const int seg = tid & 3;
  const int c0  = seg * 16;
  const int sw  = (row & 7) * 8;
  u16* op = x_t + ((size_t)b * TPAD + t0 + row) * 64 + c0;
  *(uint4*)op       = *(const uint4*)&lt[row][c0 ^ sw];        // swizzle on READ
  *(uint4*)(op + 8) = *(const uint4*)&lt[row][(c0 + 8) ^ sw];
  if (tt == 0) {
    uint4 z = make_uint4(0u, 0u, 0u, 0u);
    uint4* pz = (uint4*)(x_t + ((size_t)b * TPAD + Tn) * 64);
    pz[tid] = z;
  }
}

// ---------------------------------------------------------------------------
// Kernel 2: implicit-GEMM conv, NOW with pipelined weight staging:
//  - 21 groups of 2 c-iterations, weights triple-buffered (3 x 8 KB LDS)
//  - stages issued 2 groups ahead via global_load_lds
//  - counted s_waitcnt vmcnt(2) + raw s_barrier: ONE barrier per group,
//    never draining vmcnt to 0 in the main loop (T3/T4)
//  - s_setprio(1) around MFMA clusters (T5 — pays once phases role-split)
// LDS: 35840 (xs) + 24576 (wsw) + 512 (sred) = 60928 B -> 2 blocks/CU kept.
// Epilogue (BN stats + y store) unchanged except uniform full-tile fast path.
// ---------------------------------------------------------------------------
__global__ __launch_bounds__(256, 2) void conv_mfma(const u16* __restrict__ x_t,
                                                    const u16* __restrict__ wf1,
                                                    const u16* __restrict__ wf2,
                                                    u16* __restrict__ y1,
                                                    u16* __restrict__ y2,
                                                    float* __restrict__ stats) {
  __shared__ u16 xs[XROWS * 64];       // 35840 B
  __shared__ u16 wsw[3][4096];         // 3 x 8192 B (8 chunks of 1 KB each)
  __shared__ float sred[128];          // 512 B

  const int bid  = blockIdx.x;
  const int cv   = bid & 1;
  const int tmp  = bid >> 1;
  const int tile = tmp & 63;
  const int b    = tmp >> 6;
  const int t0   = tile * TILE;
  const int tid  = threadIdx.x;
  const int w    = tid >> 6;    // wave id
  const int lane = tid & 63;
  const int q    = lane >> 4;
  const int r    = lane & 15;
  const u16* wf  = cv ? wf2 : wf1;

  if (tid < 128) sred[tid] = 0.f;
  __syncthreads();   // sred init visible before epilogue atomics (formal)

  // stage weights for group gg into buffer m: 8 chunks, 2 per wave
  auto stage_w = [&](int m, int gg) {
    const u16* wg = wf + (size_t)gg * 4096;
    gload_lds16(wg + (size_t)w * 512 + lane * 8,       &wsw[m][w * 512]);
    gload_lds16(wg + (size_t)(w + 4) * 512 + lane * 8, &wsw[m][(w + 4) * 512]);
  };

  // stage x tile: 280 rows * 128B = 35 x 1KB chunks
  const u16* xg = x_t + ((size_t)b * TPAD + t0) * 64;
  for (int s = w; s < 35; s += 4)
    gload_lds16(xg + (size_t)s * 512 + lane * 8, &xs[s * 512]);
  stage_w(0, 0);
  stage_w(1, 1);

  f32x4 acc[4][4];
#pragma unroll
  for (int a = 0; a < 4; ++a)
#pragma unroll
    for (int t = 0; t < 4; ++t)
      acc[a][t] = (f32x4){0.f, 0.f, 0.f, 0.f};

  int mc = 0;        // buffer being computed
  int ms = 2;        // buffer being staged (g+2)
  for (int g = 0; g < 21; ++g) {
    // per-wave: outstanding = group g (2) + group g+1 (2) [+ x tile at g=0]
    if (g < 20) asm volatile("s_waitcnt vmcnt(2)" ::: "memory");
    else        asm volatile("s_waitcnt vmcnt(0)" ::: "memory");
    __builtin_amdgcn_s_barrier();            // raw: no vmcnt(0) drain
    if (g < 19) stage_w(ms, g + 2);          // overwrites buf read at g-1: safe

#pragma unroll
    for (int cl = 0; cl < 2; ++cl) {
      const int c  = g * 2 + cl;
      const int k  = c >> 1;
      const int cb = (c & 1) * 32;
      bf16x8 af[4];
#pragma unroll
      for (int ct = 0; ct < 4; ++ct)
        af[ct] = *(const bf16x8*)&wsw[mc][((cl * 4 + ct) * 64 + lane) * 8];
      bf16x8 bx[4];
#pragma unroll
      for (int tt = 0; tt < 4; ++tt) {
        int p = w * 64 + tt * 16 + r + k;
        int cidx = (cb + q * 8) ^ ((p & 7) * 8);   // bake the x_t XOR swizzle
        bx[tt] = *(const bf16x8*)&xs[p * 64 + cidx];
      }
      __builtin_amdgcn_s_setprio(1);
#pragma unroll
      for (int ct = 0; ct < 4; ++ct)
#pragma unroll
        for (int tt = 0; tt < 4; ++tt)
          acc[ct][tt] = __builtin_amdgcn_mfma_f32_16x16x32_bf16(af[ct], bx[tt], acc[ct][tt], 0, 0, 0);
      __builtin_amdgcn_s_setprio(0);
    }
    mc = (mc == 2) ? 0 : mc + 1;
    ms = (ms == 2) ? 0 : ms + 1;
  }

  // ---- BN statistics (mask t >= TCn; only tile 63 needs the mask) ----
  const bool full = (t0 + TILE <= TCn);
#pragma unroll
  for (int ct = 0; ct < 4; ++ct)
#pragma unroll
    for (int i = 0; i < 4; ++i) {
      float sv = 0.f, sq = 0.f;
      if (full) {
#pragma unroll
        for (int tt = 0; tt < 4; ++tt) {
          float v = acc[ct][tt][i];
          sv += v; sq += v * v;
        }
      } else {
#pragma unroll
        for (int tt = 0; tt < 4; ++tt) {
          int tg = t0 + w * 64 + tt * 16 + r;
          if (tg < TCn) {
            float v = acc[ct][tt][i];
            sv += v; sq += v * v;
          }
        }
      }
#pragma unroll
      for (int m = 1; m < 16; m <<= 1) {
        sv += __shfl_xor(sv, m, 64);
        sq += __shfl_xor(sq, m, 64);
      }
      if (r == 0) {
        int co = ct * 16 + q * 4 + i;
        atomicAdd(&sred[co * 2], sv);
        atomicAdd(&sred[co * 2 + 1], sq);
      }
    }

  __syncthreads();   // all waves done reading xs before reuse as y staging

  // ---- store y_t[b][t][co] bf16 via LDS transpose (reuse xs) ----
  u16* ys = xs;
#pragma unroll
  for (int ct = 0; ct < 4; ++ct)
#pragma unroll
    for (int tt = 0; tt < 4; ++tt) {
      int tl = w * 64 + tt * 16 + r;
#pragma unroll
      for (int i = 0; i < 4; ++i) {
        int co = ct * 16 + q * 4 + i;
        ys[tl * 64 + co] = f2bf(acc[ct][tt][i]);
      }
    }
  __syncthreads();
  u16* yo = (cv ? y2 : y1) + ((size_t)b * Tn + t0) * 64;
#pragma unroll
  for (int m = 0; m < 8; ++m) {
    int idx = (m * 256 + tid) * 8;
    *(uint4*)(yo + idx) = *(const uint4*)(ys + idx);
  }
  if (tid < 128) atomicAdd(&stats[cv * 128 + tid], sred[tid]);
}

// ---------------------------------------------------------------------------
// Kernel 3: SPP, both tensors. NOW: grid = (b, 1/64th of t) = 2048 blocks
// (8 blocks/CU -> full occupancy vs previous 2 waves/SIMD), full-chunk fast
// path unrolled x4 so 8 independent loads are in flight per wave.
// Math/reduction/atomics identical to the proven version.
// ---------------------------------------------------------------------------
__global__ __launch_bounds__(256) void spp(const u16* __restrict__ y1,
                                           const u16* __restrict__ y2,
                                           const float* __restrict__ stats,
                                           const float* __restrict__ g1v,
                                           const float* __restrict__ b1v,
                                           const float* __restrict__ g2v,
                                           const float* __restrict__ b2v,
                                           const int* __restrict__ orig_len,
                                           u32* __restrict__ featU) {
  const int bx = blockIdx.x;
  const int b  = bx >> 6;
  const int ch = bx & 63;
  const int tid  = threadIdx.x;
  const int g    = tid & 15;       // channel group: co = g*4 .. g*4+3
  const int trow = tid >> 4;       // 0..15
  const int co0  = g * 4;
  const int L     = orig_len[b] - 20;
  const int str2  = L >> 1;
  const int kern2 = L - str2;
  const float Nf = 32.0f * 16364.0f;
  float a1[4], c1[4], a2[4], c2[4];
#pragma unroll
  for (int j = 0; j < 4; ++j) {
    int co = co0 + j;
    float s, sq, mean, var;
    s = stats[co * 2]; sq = stats[co * 2 + 1];
    mean = s / Nf; var = sq / Nf - mean * mean; if (var < 0.f) var = 0.f;
    a1[j] = g1v[co] * rsqrtf(var + 1e-5f);
    c1[j] = b1v[co] - mean * a1[j];
    s = stats[128 + co * 2]; sq = stats[128 + co * 2 + 1];
    mean = s / Nf; var = sq / Nf - mean * mean; if (var < 0.f) var = 0.f;
    a2[j] = g2v[co] * rsqrtf(var + 1e-5f);
    c2[j] = b2v[co] - mean * a2[j];
  }
  float m1[4] = {-3.4e38f,-3.4e38f,-3.4e38f,-3.4e38f};
  float m2[4] = {-3.4e38f,-3.4e38f,-3.4e38f,-3.4e38f};
  float s0[4] = {0,0,0,0}, sb0[4] = {0,0,0,0}, sb1[4] = {0,0,0,0};
  const int tbase = ch * 256;
  int tend = tbase + 256;
  if (tend > L) tend = L;
  const u16* p1 = y1 + (size_t)b * Tn * 64 + co0;
  const u16* p2 = y2 + (size_t)b * Tn * 64 + co0;

  auto body = [&](int t) {
    uint2 v1 = *(const uint2*)(p1 + (size_t)t * 64);
    uint2 v2 = *(const uint2*)(p2 + (size_t)t * 64);
    float f1[4] = { bf2f(v1.x & 0xffffu), bf2f(v1.x >> 16),
                    bf2f(v1.y & 0xffffu), bf2f(v1.y >> 16) };
    float f2[4] = { bf2f(v2.x & 0xffffu), bf2f(v2.x >> 16),
                    bf2f(v2.y & 0xffffu), bf2f(v2.y >> 16) };
    bool in0 = (t < kern2), in1 = (t >= str2);   // t < L via tend
#pragma unroll
    for (int j = 0; j < 4; ++j) {
      float z1 = leaky(fmaf(a1[j], f1[j], c1[j]));
      float z2 = leaky(fmaf(a2[j], f2[j], c2[j]));
      s0[j] += z2;
      if (in0) { m1[j] = fmaxf(m1[j], z1); sb0[j] += z2; }
      if (in1) { m2[j] = fmaxf(m2[j], z1); sb1[j] += z2; }
    }
  };

  if (tend == tbase + 256) {
    // full chunk: exactly 16 iterations, unroll x4 for load-level parallelism
    for (int it = 0; it < 16; it += 4) {
#pragma unroll
      for (int u = 0; u < 4; ++u)
        body(tbase + trow + (it + u) * 16);
    }
  } else {
    for (int t = tbase + trow; t < tend; t += 16)
      body(t);
  }

  // reduce across the 4 row-lanes in this wave sharing g (lane>>4)
#pragma unroll
  for (int m = 16; m <= 32; m <<= 1) {
#pragma unroll
    for (int j = 0; j < 4; ++j) {
      m1[j]  = fmaxf(m1[j], __shfl_xor(m1[j], m, 64));
      m2[j]  = fmaxf(m2[j], __shfl_xor(m2[j], m, 64));
      s0[j]  += __shfl_xor(s0[j],  m, 64);
      sb0[j] += __shfl_xor(sb0[j], m, 64);
      sb1[j] += __shfl_xor(sb1[j], m, 64);
    }
  }
  if (((tid & 63) >> 4) == 0) {
    u32* fb = featU + (size_t)b * 384;
    float* ff = (float*)fb;
#pragma unroll
    for (int j = 0; j < 4; ++j) {
      int co = co0 + j;
      u32 e1 = encf(m1[j]), e2 = encf(m2[j]);
      atomicMax(&fb[co], e1 > e2 ? e1 : e2);   // level0 max = max(bin0,bin1)
      atomicMax(&fb[64 + co * 2], e1);
      atomicMax(&fb[64 + co * 2 + 1], e2);
      atomicAdd(&ff[192 + co], s0[j]);
      atomicAdd(&ff[256 + co * 2], sb0[j]);
      atomicAdd(&ff[256 + co * 2 + 1], sb1[j]);
    }
  }
}

// ---------------------------------------------------------------------------
// Kernel 4: FC. feat(32,384) @ fc_w^T(384,2) + fc_b. NOW 32 blocks (one per b)
// x 128 threads (64 lanes per output n): 6 coalesced loads/lane + shfl reduce.
// ---------------------------------------------------------------------------
__global__ __launch_bounds__(128) void fc(const u32* __restrict__ featU,
                                          const int* __restrict__ orig_len,
                                          const float* __restrict__ fc_w,
                                          const float* __restrict__ fc_b,
                                          float* __restrict__ out) {
  const int b    = blockIdx.x;
  const int tid  = threadIdx.x;        // 128
  const int n    = tid >> 6;
  const int lane = tid & 63;
  const int L = orig_len[b] - 20;
  const int kern2 = L - (L >> 1);
  const u32* fb = featU + (size_t)b * 384;
  const float* ff = (const float*)fb;
  float acc = 0.f;
#pragma unroll
  for (int jj = 0; jj < 6; ++jj) {
    int j = jj * 64 + lane;            // branch below is uniform per jj
    float fv;
    if (j < 192)      fv = decf(fb[j]);
    else if (j < 256) fv = ff[j] / (float)L;
    else              fv = ff[j] / (float)kern2;
    acc += fv * fc_w[n * 384 + j];
  }
#pragma unroll
  for (int m = 1; m < 64; m <<= 1) acc += __shfl_xor(acc, m, 64);
  if (lane == 0) out[b * 2 + n] = acc + fc_b[n];
}

// ---------------------------------------------------------------------------
extern "C" void kernel_launch(void* const* d_in, const int* in_sizes, int n_in,
                              void* d_out, int out_size, void* d_ws, size_t ws_size,
                              hipStream_t stream) {
  const float* x        = (const float*)d_in[0];
  const int*   orig_len = (const int*)d_in[1];
  const float* w1  = (const float*)d_in[2];
  const float* g1  = (const float*)d_in[3];
  const float* b1  = (const float*)d_in[4];
  const float* w2  = (const float*)d_in[5];
  const float* g2  = (const float*)d_in[6];
  const float* b2  = (const float*)d_in[7];
  const float* fcw = (const float*)d_in[8];
  const float* fcb = (const float*)d_in[9];
  float* out = (float*)d_out;

  char* ws = (char*)d_ws;
  const size_t XT_BYTES = (size_t)Bn * TPAD * 64 * 2;    // 67,239,936
  const size_t Y_BYTES  = (size_t)Bn * Tn * 64 * 2;      // 67,108,864
  const size_t WF_BYTES = (size_t)42 * 4 * 64 * 8 * 2;   // 172,032
  size_t off = 0;
  u16* x_t = (u16*)(ws + off); off += XT_BYTES;
  u16* y1  = (u16*)(ws + off); off += Y_BYTES;
  u16* y2  = (u16*)(ws + off); off += Y_BYTES;
  u16* wf1 = (u16*)(ws + off); off += WF_BYTES;
  u16* wf2 = (u16*)(ws + off); off += WF_BYTES;
  float* stats = (float*)(ws + off);                 // 1024 B (2cv x 64co x {s,sq})
  u32*   featU = (u32*)(ws + off + 1024);            // 32*384*4 = 49152 B
  const size_t SMALL_BYTES = 1024 + 49152;

  hipMemsetAsync(ws + off, 0, SMALL_BYTES, stream);
  transpose_x<<<Bn * 256 + 84, 256, 0, stream>>>(x, x_t, w1, w2, wf1, wf2);
  conv_mfma<<<Bn * 64 * 2, 256, 0, stream>>>(x_t, wf1, wf2, y1, y2, stats);
  spp<<<Bn * 64, 256, 0, stream>>>(y1, y2, stats, g1, b1, g2, b2, orig_len, featU);
  fc<<<Bn, 128, 0, stream>>>(featU, orig_len, fcw, fcb, out);
  (void)in_sizes; (void)n_in; (void)out_size; (void)ws_size;
}

// Round 2
// 521.524 us; speedup vs baseline: 1.1346x; 1.1346x over previous
//
#include <hip/hip_runtime.h>

#define AS1 __attribute__((address_space(1)))
#define AS3 __attribute__((address_space(3)))

using u16 = unsigned short;
using u32 = unsigned int;
typedef __attribute__((ext_vector_type(8))) short bf16x8;
typedef __attribute__((ext_vector_type(4))) float f32x4;

constexpr int Bn    = 32;
constexpr int Tn    = 16384;
constexpr int TCn   = 16364;   // Tn - (K-1)
constexpr int TILE  = 512;     // conv block t-tile (32 tiles exactly)
constexpr int XROWS = 536;     // staged rows per conv block (512+21 -> 536, 67 KB-chunks)
constexpr int TPAD  = 16416;   // Tn + 32 zero pad rows

__device__ __forceinline__ u16 f2bf(float f) {
  union { float f; u32 u; } v; v.f = f;
  u32 u = v.u;
  u += 0x7fffu + ((u >> 16) & 1u);   // RNE
  return (u16)(u >> 16);
}
__device__ __forceinline__ float bf2f(u32 h) {
  union { u32 u; float f; } v; v.u = h << 16; return v.f;
}
// order-preserving float<->uint for atomicMax on signed floats
__device__ __forceinline__ u32 encf(float f) {
  union { float f; u32 u; } v; v.f = f;
  return (v.u & 0x80000000u) ? ~v.u : (v.u | 0x80000000u);
}
__device__ __forceinline__ float decf(u32 u) {
  union { u32 u; float f; } v;
  v.u = (u & 0x80000000u) ? (u ^ 0x80000000u) : ~u;
  return v.f;
}
__device__ __forceinline__ void gload_lds16(const void* g, void* l) {
  __builtin_amdgcn_global_load_lds((const AS1 u32*)g, (AS3 u32*)l, 16, 0, 0);
}
__device__ __forceinline__ float leaky(float z) { return z > 0.f ? z : 0.01f * z; }

// ---------------------------------------------------------------------------
// Kernel 1: (a) x -> x_t[b][t][ci ^ ((t&7)*8)] bf16 + zero pad (b64 LDS writes,
// swizzle applied on LDS read — verified correct);
// (b) tail blocks repack weights into MFMA A-fragment order.
// UNCHANGED from the 483.6 us measured round.
// ---------------------------------------------------------------------------
__global__ __launch_bounds__(256) void transpose_x(const float* __restrict__ x,
                                                   u16* __restrict__ x_t,
                                                   const float* __restrict__ w1,
                                                   const float* __restrict__ w2,
                                                   u16* __restrict__ wf1,
                                                   u16* __restrict__ wf2) {
  __shared__ u16 lt[64][64];               // 8 KB, [t][ci] (plain)
  const int bx  = blockIdx.x;
  const int tid = threadIdx.x;

  if (bx >= Bn * 256) {                    // ---- weight repack (84 blocks) ----
    const int bxx = bx - Bn * 256;
    const int cv  = bxx / 42;
    const int c   = bxx % 42;
    const float* w = cv ? w2 : w1;
    u16* wf = cv ? wf2 : wf1;
    const int ct   = tid >> 6;
    const int lane = tid & 63;
    const int q  = lane >> 4;
    const int rr = lane & 15;
    const int k  = c >> 1;
    const int cb = (c & 1) * 32;
    const int co = ct * 16 + rr;
    u16 us[8] __attribute__((aligned(16)));
#pragma unroll
    for (int j = 0; j < 8; ++j) {
      int ci = cb + q * 8 + j;
      us[j] = f2bf(w[((size_t)co * 64 + ci) * 21 + k]);
    }
    *(uint4*)&wf[((size_t)(c * 4 + ct) * 64 + lane) * 8] = *(const uint4*)us;
    return;
  }

  const int b   = bx >> 8;
  const int tt  = bx & 255;
  const int t0  = tt * 64;
  const int ci0 = (tid & 15) * 4;
  const int tl0 = (tid >> 4) * 4;
  float4 v[4];
#pragma unroll
  for (int j = 0; j < 4; ++j)
    v[j] = *(const float4*)(x + (size_t)(b * 64 + ci0 + j) * Tn + t0 + tl0);
  float vr[4][4] = {{v[0].x,v[0].y,v[0].z,v[0].w},{v[1].x,v[1].y,v[1].z,v[1].w},
                    {v[2].x,v[2].y,v[2].z,v[2].w},{v[3].x,v[3].y,v[3].z,v[3].w}};
#pragma unroll
  for (int e = 0; e < 4; ++e) {
    int tl = tl0 + e;
    u32 lo = (u32)f2bf(vr[0][e]) | ((u32)f2bf(vr[1][e]) << 16);
    u32 hi = (u32)f2bf(vr[2][e]) | ((u32)f2bf(vr[3][e]) << 16);
    uint2 pk = make_uint2(lo, hi);
    *(uint2*)&lt[tl][ci0] = pk;              // ds_write_b64, PLAIN index
  }
  __syncthreads();
  const int row = tid >> 2;
  const int seg = tid & 3;
  const int c0  = seg * 16;
  const int sw  = (row & 7) * 8;
  u16* op = x_t + ((size_t)b * TPAD + t0 + row) * 64 + c0;
  *(uint4*)op       = *(const uint4*)&lt[row][c0 ^ sw];        // swizzle on READ
  *(uint4*)(op + 8) = *(const uint4*)&lt[row][(c0 + 8) ^ sw];
  if (tt == 0) {
    uint4 z = make_uint4(0u, 0u, 0u, 0u);
    uint4* pz = (uint4*)(x_t + ((size_t)b * TPAD + Tn) * 64);
    pz[tid] = z;
  }
}

// ---------------------------------------------------------------------------
// Kernel 2: implicit-GEMM conv, redesigned tile:
//  - TILE=512 t-rows per block, 4 waves, each wave 128 t x 64 co -> acc[4][8]
//    (reads/MFMA drops 0.5 -> 0.375: LDS pipe goes below MFMA pipe)
//  - weights double-buffered (2 x 28 KB), staged one group ahead:
//    barrier(buf free) -> issue stage(g+1) -> s_waitcnt vmcnt(7) -> barrier ->
//    compute 224 MFMAs/wave.  vmcnt never drains to 0 mid-loop; compute per
//    sync region stays large (round-1's 32-MFMA regions were the regression).
//  - 1 block/CU (LDS 126,464 B), half the blocks/barriers/epilogues per FLOP.
//  - epilogue ys writes XOR-swizzled uint2 (was 16-way bank-conflicted scalar).
// ---------------------------------------------------------------------------
__global__ __launch_bounds__(256, 1) void conv_mfma(const u16* __restrict__ x_t,
                                                    const u16* __restrict__ wf1,
                                                    const u16* __restrict__ wf2,
                                                    u16* __restrict__ y1,
                                                    u16* __restrict__ y2,
                                                    float* __restrict__ stats) {
  __shared__ u16 xs[XROWS * 64];       // 68,608 B (67 x 1KB chunks)
  __shared__ u16 wsw[2][7 * 4 * 64 * 8]; // 2 x 28,672 B
  __shared__ float sred[128];          // 512 B   -> total 126,464 B

  const int bid  = blockIdx.x;
  const int cv   = bid & 1;
  const int tmp  = bid >> 1;
  const int tile = tmp & 31;
  const int b    = tmp >> 5;
  const int t0   = tile * TILE;
  const int tid  = threadIdx.x;
  const int w    = tid >> 6;    // wave id (0..3), wave row base = w*128
  const int lane = tid & 63;
  const int q    = lane >> 4;
  const int r    = lane & 15;
  const u16* wf  = cv ? wf2 : wf1;

  if (tid < 128) sred[tid] = 0.f;

  // stage x tile: 536 rows * 128B = 67 x 1KB chunks
  const u16* xg = x_t + ((size_t)b * TPAD + t0) * 64;
  for (int s = w; s < 67; s += 4)
    gload_lds16(xg + (size_t)s * 512 + lane * 8, &xs[s * 512]);
  // stage weight group 0 into buffer 0 (28 x 1KB chunks, 7 per wave)
  for (int s = w; s < 28; s += 4)
    gload_lds16(wf + (size_t)s * 512 + lane * 8, &wsw[0][s * 512]);

  f32x4 acc[4][8];
#pragma unroll
  for (int a = 0; a < 4; ++a)
#pragma unroll
    for (int t = 0; t < 8; ++t)
      acc[a][t] = (f32x4){0.f, 0.f, 0.f, 0.f};

  for (int g = 0; g < 6; ++g) {
    __builtin_amdgcn_s_barrier();        // buffer (g+1)&1 no longer being read
    if (g < 5) {
      const u16* wg = wf + (size_t)(g + 1) * 14336;
      for (int s = w; s < 28; s += 4)
        gload_lds16(wg + (size_t)s * 512 + lane * 8, &wsw[(g + 1) & 1][s * 512]);
      // wait x + group g landed; group g+1's 7 chunks may remain in flight
      asm volatile("s_waitcnt vmcnt(7)" ::: "memory");
    } else {
      asm volatile("s_waitcnt vmcnt(0)" ::: "memory");
    }
    __builtin_amdgcn_s_barrier();        // all waves' group-g data visible
    __builtin_amdgcn_sched_barrier(0);
    const int mb = g & 1;
#pragma unroll
    for (int cl = 0; cl < 7; ++cl) {
      const int c  = g * 7 + cl;
      const int k  = c >> 1;
      const int cb = (c & 1) * 32;
      bf16x8 af[4];
#pragma unroll
      for (int ct = 0; ct < 4; ++ct)
        af[ct] = *(const bf16x8*)&wsw[mb][((cl * 4 + ct) * 64 + lane) * 8];
      bf16x8 bx[8];
#pragma unroll
      for (int tt = 0; tt < 8; ++tt) {
        int p = w * 128 + tt * 16 + r + k;
        int cidx = (cb + q * 8) ^ ((p & 7) * 8);   // bake the x_t XOR swizzle
        bx[tt] = *(const bf16x8*)&xs[p * 64 + cidx];
      }
#pragma unroll
      for (int ct = 0; ct < 4; ++ct)
#pragma unroll
        for (int tt = 0; tt < 8; ++tt)
          acc[ct][tt] = __builtin_amdgcn_mfma_f32_16x16x32_bf16(af[ct], bx[tt], acc[ct][tt], 0, 0, 0);
    }
  }

  // ---- BN statistics (mask t >= TCn; only the last tile needs the mask) ----
  const bool full_t = (t0 + TILE <= TCn);
#pragma unroll
  for (int ct = 0; ct < 4; ++ct)
#pragma unroll
    for (int i = 0; i < 4; ++i) {
      float sv = 0.f, sq = 0.f;
      if (full_t) {
#pragma unroll
        for (int tt = 0; tt < 8; ++tt) {
          float v = acc[ct][tt][i];
          sv += v; sq += v * v;
        }
      } else {
#pragma unroll
        for (int tt = 0; tt < 8; ++tt) {
          int tg = t0 + w * 128 + tt * 16 + r;
          if (tg < TCn) {
            float v = acc[ct][tt][i];
            sv += v; sq += v * v;
          }
        }
      }
#pragma unroll
      for (int m = 1; m < 16; m <<= 1) {
        sv += __shfl_xor(sv, m, 64);
        sq += __shfl_xor(sq, m, 64);
      }
      if (r == 0) {
        int co = ct * 16 + q * 4 + i;
        atomicAdd(&sred[co * 2], sv);
        atomicAdd(&sred[co * 2 + 1], sq);
      }
    }

  __syncthreads();   // all waves done reading xs before reuse as y staging

  // ---- store y_t[b][t][co] via LDS transpose (reuse xs), XOR-swizzled ----
  u16* ys = xs;
#pragma unroll
  for (int ct = 0; ct < 4; ++ct)
#pragma unroll
    for (int tt = 0; tt < 8; ++tt) {
      int tl = w * 128 + tt * 16 + r;
      int sw = (tl & 7) * 8;
      int co0 = (ct * 16 + q * 4) ^ sw;        // XOR hits bits 3-5 only: stays 4-aligned
      u32 lo = (u32)f2bf(acc[ct][tt][0]) | ((u32)f2bf(acc[ct][tt][1]) << 16);
      u32 hi = (u32)f2bf(acc[ct][tt][2]) | ((u32)f2bf(acc[ct][tt][3]) << 16);
      *(uint2*)&ys[tl * 64 + co0] = make_uint2(lo, hi);
    }
  __syncthreads();
  u16* yo = (cv ? y2 : y1) + ((size_t)b * Tn + t0) * 64;
#pragma unroll
  for (int m = 0; m < 16; ++m) {
    int flat = m * 256 + tid;
    int row  = flat >> 3;
    int c0   = (flat & 7) * 8;
    int sw   = (row & 7) * 8;
    *(uint4*)(yo + (size_t)row * 64 + c0) = *(const uint4*)&ys[row * 64 + (c0 ^ sw)];
  }
  if (tid < 128) atomicAdd(&stats[cv * 128 + tid], sred[tid]);
}

// ---------------------------------------------------------------------------
// Kernel 3: SPP, both tensors, vectorized. Block = (b, 1/16th of t).
// REVERTED byte-identical to the 483.6 us round-0 version.
// ---------------------------------------------------------------------------
__global__ __launch_bounds__(256) void spp(const u16* __restrict__ y1,
                                           const u16* __restrict__ y2,
                                           const float* __restrict__ stats,
                                           const float* __restrict__ g1v,
                                           const float* __restrict__ b1v,
                                           const float* __restrict__ g2v,
                                           const float* __restrict__ b2v,
                                           const int* __restrict__ orig_len,
                                           u32* __restrict__ featU) {
  const int bx = blockIdx.x;
  const int b  = bx >> 4;
  const int ch = bx & 15;
  const int tid  = threadIdx.x;
  const int g    = tid & 15;       // channel group: co = g*4 .. g*4+3
  const int trow = tid >> 4;       // 0..15
  const int co0  = g * 4;
  const int L     = orig_len[b] - 20;
  const int str2  = L >> 1;
  const int kern2 = L - str2;
  const float Nf = 32.0f * 16364.0f;
  float a1[4], c1[4], a2[4], c2[4];
#pragma unroll
  for (int j = 0; j < 4; ++j) {
    int co = co0 + j;
    float s, sq, mean, var;
    s = stats[co * 2]; sq = stats[co * 2 + 1];
    mean = s / Nf; var = sq / Nf - mean * mean; if (var < 0.f) var = 0.f;
    a1[j] = g1v[co] * rsqrtf(var + 1e-5f);
    c1[j] = b1v[co] - mean * a1[j];
    s = stats[128 + co * 2]; sq = stats[128 + co * 2 + 1];
    mean = s / Nf; var = sq / Nf - mean * mean; if (var < 0.f) var = 0.f;
    a2[j] = g2v[co] * rsqrtf(var + 1e-5f);
    c2[j] = b2v[co] - mean * a2[j];
  }
  float m1[4] = {-3.4e38f,-3.4e38f,-3.4e38f,-3.4e38f};
  float m2[4] = {-3.4e38f,-3.4e38f,-3.4e38f,-3.4e38f};
  float s0[4] = {0,0,0,0}, sb0[4] = {0,0,0,0}, sb1[4] = {0,0,0,0};
  const int tbase = ch * 1024;
  int tend = tbase + 1024;
  if (tend > L) tend = L;
  const u16* p1 = y1 + (size_t)b * Tn * 64 + co0;
  const u16* p2 = y2 + (size_t)b * Tn * 64 + co0;
  for (int t = tbase + trow; t < tend; t += 16) {
    uint2 v1 = *(const uint2*)(p1 + (size_t)t * 64);
    uint2 v2 = *(const uint2*)(p2 + (size_t)t * 64);
    float f1[4] = { bf2f(v1.x & 0xffffu), bf2f(v1.x >> 16),
                    bf2f(v1.y & 0xffffu), bf2f(v1.y >> 16) };
    float f2[4] = { bf2f(v2.x & 0xffffu), bf2f(v2.x >> 16),
                    bf2f(v2.y & 0xffffu), bf2f(v2.y >> 16) };
    bool in0 = (t < kern2), in1 = (t >= str2);   // t < L via tend
#pragma unroll
    for (int j = 0; j < 4; ++j) {
      float z1 = leaky(fmaf(a1[j], f1[j], c1[j]));
      float z2 = leaky(fmaf(a2[j], f2[j], c2[j]));
      s0[j] += z2;
      if (in0) { m1[j] = fmaxf(m1[j], z1); sb0[j] += z2; }
      if (in1) { m2[j] = fmaxf(m2[j], z1); sb1[j] += z2; }
    }
  }
  // reduce across the 4 row-lanes in this wave sharing g (lane>>4)
#pragma unroll
  for (int m = 16; m <= 32; m <<= 1) {
#pragma unroll
    for (int j = 0; j < 4; ++j) {
      m1[j]  = fmaxf(m1[j], __shfl_xor(m1[j], m, 64));
      m2[j]  = fmaxf(m2[j], __shfl_xor(m2[j], m, 64));
      s0[j]  += __shfl_xor(s0[j],  m, 64);
      sb0[j] += __shfl_xor(sb0[j], m, 64);
      sb1[j] += __shfl_xor(sb1[j], m, 64);
    }
  }
  if (((tid & 63) >> 4) == 0) {
    u32* fb = featU + (size_t)b * 384;
    float* ff = (float*)fb;
#pragma unroll
    for (int j = 0; j < 4; ++j) {
      int co = co0 + j;
      u32 e1 = encf(m1[j]), e2 = encf(m2[j]);
      atomicMax(&fb[co], e1 > e2 ? e1 : e2);   // level0 max = max(bin0,bin1)
      atomicMax(&fb[64 + co * 2], e1);
      atomicMax(&fb[64 + co * 2 + 1], e2);
      atomicAdd(&ff[192 + co], s0[j]);
      atomicAdd(&ff[256 + co * 2], sb0[j]);
      atomicAdd(&ff[256 + co * 2 + 1], sb1[j]);
    }
  }
}

// ---------------------------------------------------------------------------
// Kernel 4: FC. feat(32,384) @ fc_w^T(384,2) + fc_b. Decode maxes, scale avgs.
// REVERTED to the round-0 proven version.
// ---------------------------------------------------------------------------
__global__ void fc(const u32* __restrict__ featU,
                   const int* __restrict__ orig_len,
                   const float* __restrict__ fc_w,
                   const float* __restrict__ fc_b,
                   float* __restrict__ out) {
  const int tid  = threadIdx.x;        // 256
  const int pair = tid >> 2;           // (b,n)
  const int part = tid & 3;
  const int b = pair >> 1;
  const int n = pair & 1;
  const int L = orig_len[b] - 20;
  const int kern2 = L - (L >> 1);
  const u32* fb = featU + (size_t)b * 384;
  const float* ff = (const float*)fb;
  float acc = 0.f;
  for (int j = part; j < 384; j += 4) {
    float fv;
    if (j < 192)      fv = decf(fb[j]);
    else if (j < 256) fv = ff[j] / (float)L;
    else              fv = ff[j] / (float)kern2;
    acc += fv * fc_w[n * 384 + j];
  }
  acc += __shfl_xor(acc, 1, 64);
  acc += __shfl_xor(acc, 2, 64);
  if (part == 0) out[b * 2 + n] = acc + fc_b[n];
}

// ---------------------------------------------------------------------------
extern "C" void kernel_launch(void* const* d_in, const int* in_sizes, int n_in,
                              void* d_out, int out_size, void* d_ws, size_t ws_size,
                              hipStream_t stream) {
  const float* x        = (const float*)d_in[0];
  const int*   orig_len = (const int*)d_in[1];
  const float* w1  = (const float*)d_in[2];
  const float* g1  = (const float*)d_in[3];
  const float* b1  = (const float*)d_in[4];
  const float* w2  = (const float*)d_in[5];
  const float* g2  = (const float*)d_in[6];
  const float* b2  = (const float*)d_in[7];
  const float* fcw = (const float*)d_in[8];
  const float* fcb = (const float*)d_in[9];
  float* out = (float*)d_out;

  char* ws = (char*)d_ws;
  const size_t XT_BYTES = (size_t)Bn * TPAD * 64 * 2;    // 67,239,936
  const size_t Y_BYTES  = (size_t)Bn * Tn * 64 * 2;      // 67,108,864
  const size_t WF_BYTES = (size_t)42 * 4 * 64 * 8 * 2;   // 172,032
  size_t off = 0;
  u16* x_t = (u16*)(ws + off); off += XT_BYTES;
  u16* y1  = (u16*)(ws + off); off += Y_BYTES;
  u16* y2  = (u16*)(ws + off); off += Y_BYTES;
  u16* wf1 = (u16*)(ws + off); off += WF_BYTES;
  u16* wf2 = (u16*)(ws + off); off += WF_BYTES;
  float* stats = (float*)(ws + off);                 // 1024 B (2cv x 64co x {s,sq})
  u32*   featU = (u32*)(ws + off + 1024);            // 32*384*4 = 49152 B
  const size_t SMALL_BYTES = 1024 + 49152;

  hipMemsetAsync(ws + off, 0, SMALL_BYTES, stream);
  transpose_x<<<Bn * 256 + 84, 256, 0, stream>>>(x, x_t, w1, w2, wf1, wf2);
  conv_mfma<<<Bn * 32 * 2, 256, 0, stream>>>(x_t, wf1, wf2, y1, y2, stats);
  spp<<<Bn * 16, 256, 0, stream>>>(y1, y2, stats, g1, b1, g2, b2, orig_len, featU);
  fc<<<1, 256, 0, stream>>>(featU, orig_len, fcw, fcb, out);
  (void)in_sizes; (void)n_in; (void)out_size; (void)ws_size;
}

// Round 3
// 466.080 us; speedup vs baseline: 1.2696x; 1.1190x over previous
//
#include <hip/hip_runtime.h>

#define AS1 __attribute__((address_space(1)))
#define AS3 __attribute__((address_space(3)))

using u16 = unsigned short;
using u32 = unsigned int;
typedef __attribute__((ext_vector_type(8))) short bf16x8;
typedef __attribute__((ext_vector_type(4))) float f32x4;

constexpr int Bn    = 32;
constexpr int Tn    = 16384;
constexpr int TCn   = 16364;   // Tn - (K-1)
constexpr int TILE  = 256;     // conv block t-tile (64 tiles exactly)
constexpr int XROWS = 280;     // staged rows per conv block
constexpr int TPAD  = 16416;   // Tn + 32 zero pad rows

__device__ __forceinline__ u16 f2bf(float f) {
  union { float f; u32 u; } v; v.f = f;
  u32 u = v.u;
  u += 0x7fffu + ((u >> 16) & 1u);   // RNE
  return (u16)(u >> 16);
}
__device__ __forceinline__ float bf2f(u32 h) {
  union { u32 u; float f; } v; v.u = h << 16; return v.f;
}
// order-preserving float<->uint for atomicMax on signed floats
__device__ __forceinline__ u32 encf(float f) {
  union { float f; u32 u; } v; v.f = f;
  return (v.u & 0x80000000u) ? ~v.u : (v.u | 0x80000000u);
}
__device__ __forceinline__ float decf(u32 u) {
  union { u32 u; float f; } v;
  v.u = (u & 0x80000000u) ? (u ^ 0x80000000u) : ~u;
  return v.f;
}
__device__ __forceinline__ void gload_lds16(const void* g, void* l) {
  __builtin_amdgcn_global_load_lds((const AS1 u32*)g, (AS3 u32*)l, 16, 0, 0);
}
__device__ __forceinline__ float leaky(float z) { return z > 0.f ? z : 0.01f * z; }

// ---------------------------------------------------------------------------
// Kernel 1: (a) x -> x_t[b][t][ci ^ ((t&7)*8)] bf16 + zero pad; (b) weight
// repack into MFMA A-fragment order. UNCHANGED from the measured rounds.
// ---------------------------------------------------------------------------
__global__ __launch_bounds__(256) void transpose_x(const float* __restrict__ x,
                                                   u16* __restrict__ x_t,
                                                   const float* __restrict__ w1,
                                                   const float* __restrict__ w2,
                                                   u16* __restrict__ wf1,
                                                   u16* __restrict__ wf2) {
  __shared__ u16 lt[64][64];               // 8 KB, [t][ci] (plain)
  const int bx  = blockIdx.x;
  const int tid = threadIdx.x;

  if (bx >= Bn * 256) {                    // ---- weight repack (84 blocks) ----
    const int bxx = bx - Bn * 256;
    const int cv  = bxx / 42;
    const int c   = bxx % 42;
    const float* w = cv ? w2 : w1;
    u16* wf = cv ? wf2 : wf1;
    const int ct   = tid >> 6;
    const int lane = tid & 63;
    const int q  = lane >> 4;
    const int rr = lane & 15;
    const int k  = c >> 1;
    const int cb = (c & 1) * 32;
    const int co = ct * 16 + rr;
    u16 us[8] __attribute__((aligned(16)));
#pragma unroll
    for (int j = 0; j < 8; ++j) {
      int ci = cb + q * 8 + j;
      us[j] = f2bf(w[((size_t)co * 64 + ci) * 21 + k]);
    }
    *(uint4*)&wf[((size_t)(c * 4 + ct) * 64 + lane) * 8] = *(const uint4*)us;
    return;
  }

  const int b   = bx >> 8;
  const int tt  = bx & 255;
  const int t0  = tt * 64;
  const int ci0 = (tid & 15) * 4;
  const int tl0 = (tid >> 4) * 4;
  float4 v[4];
#pragma unroll
  for (int j = 0; j < 4; ++j)
    v[j] = *(const float4*)(x + (size_t)(b * 64 + ci0 + j) * Tn + t0 + tl0);
  float vr[4][4] = {{v[0].x,v[0].y,v[0].z,v[0].w},{v[1].x,v[1].y,v[1].z,v[1].w},
                    {v[2].x,v[2].y,v[2].z,v[2].w},{v[3].x,v[3].y,v[3].z,v[3].w}};
#pragma unroll
  for (int e = 0; e < 4; ++e) {
    int tl = tl0 + e;
    u32 lo = (u32)f2bf(vr[0][e]) | ((u32)f2bf(vr[1][e]) << 16);
    u32 hi = (u32)f2bf(vr[2][e]) | ((u32)f2bf(vr[3][e]) << 16);
    uint2 pk = make_uint2(lo, hi);
    *(uint2*)&lt[tl][ci0] = pk;              // ds_write_b64, PLAIN index
  }
  __syncthreads();
  const int row = tid >> 2;
  const int seg = tid & 3;
  const int c0  = seg * 16;
  const int sw  = (row & 7) * 8;
  u16* op = x_t + ((size_t)b * TPAD + t0 + row) * 64 + c0;
  *(uint4*)op       = *(const uint4*)&lt[row][c0 ^ sw];        // swizzle on READ
  *(uint4*)(op + 8) = *(const uint4*)&lt[row][(c0 + 8) ^ sw];
  if (tt == 0) {
    uint4 z = make_uint4(0u, 0u, 0u, 0u);
    uint4* pz = (uint4*)(x_t + ((size_t)b * TPAD + Tn) * 64);
    pz[tid] = z;
  }
}

// ---------------------------------------------------------------------------
// Kernel 2: implicit-GEMM conv, BARRIER-FREE K-loop:
//  - weights are NOT staged in LDS: each wave streams its 4 A-fragments per
//    c-iter straight global->VGPR (wf is L2-resident, frag = 1 KB coalesced),
//    register double-buffered (afA/afB static names, 2-phase unroll).
//    Compiler inserts its own counted vmcnt for the register deps — the only
//    barrier in the kernel is the one after x staging.
//  - LDS = xs 35,840 B + sred 512 B -> 4 blocks/CU = 16 waves/CU (2x round-0).
//  - T5 setprio around MFMA clusters (waves free-run -> role diversity).
//  - epilogue: round-2's proven XOR-swizzled transpose (conflicts 15.7M->1M).
// ---------------------------------------------------------------------------
__global__ __launch_bounds__(256, 4) void conv_mfma(const u16* __restrict__ x_t,
                                                    const u16* __restrict__ wf1,
                                                    const u16* __restrict__ wf2,
                                                    u16* __restrict__ y1,
                                                    u16* __restrict__ y2,
                                                    float* __restrict__ stats) {
  __shared__ u16 xs[XROWS * 64];       // 35,840 B
  __shared__ float sred[128];          // 512 B -> total 36,352 B

  const int bid  = blockIdx.x;
  const int cv   = bid & 1;
  const int tmp  = bid >> 1;
  const int tile = tmp & 63;
  const int b    = tmp >> 6;
  const int t0   = tile * TILE;
  const int tid  = threadIdx.x;
  const int w    = tid >> 6;    // wave id
  const int lane = tid & 63;
  const int q    = lane >> 4;
  const int r    = lane & 15;
  const u16* wf  = cv ? wf2 : wf1;

  if (tid < 128) sred[tid] = 0.f;

  // stage x tile: 280 rows * 128B = 35 x 1KB chunks
  const u16* xg = x_t + ((size_t)b * TPAD + t0) * 64;
  for (int s = w; s < 35; s += 4)
    gload_lds16(xg + (size_t)s * 512 + lane * 8, &xs[s * 512]);

  // per-thread weight fragment pointer: frag (c,ct) at wf + c*2048 + ct*512 (+lane*8)
  const u16* wfl = wf + lane * 8;
  bf16x8 afA[4], afB[4];
#pragma unroll
  for (int ct = 0; ct < 4; ++ct) afA[ct] = *(const bf16x8*)(wfl + ct * 512);          // c=0
#pragma unroll
  for (int ct = 0; ct < 4; ++ct) afB[ct] = *(const bf16x8*)(wfl + 2048 + ct * 512);   // c=1

  __syncthreads();   // x tile (and sred init) visible; drains once, before loop

  f32x4 acc[4][4];
#pragma unroll
  for (int a = 0; a < 4; ++a)
#pragma unroll
    for (int t = 0; t < 4; ++t)
      acc[a][t] = (f32x4){0.f, 0.f, 0.f, 0.f};

  const int rowbase = w * 64 + r;

  for (int j = 0; j < 21; ++j) {
    // both phases of pair j share k = j; swizzle line is tt-invariant
    const int swl  = ((rowbase + j) & 7) * 8;
    const int cid0 = (q * 8) ^ swl;          // phase A: cb = 0
    const int cid1 = cid0 ^ 32;              // phase B: cb = 32
    // ---- phase A: c = 2j ----
    {
      bf16x8 bx[4];
#pragma unroll
      for (int tt = 0; tt < 4; ++tt)
        bx[tt] = *(const bf16x8*)&xs[(rowbase + tt * 16 + j) * 64 + cid0];
      __builtin_amdgcn_s_setprio(1);
#pragma unroll
      for (int ct = 0; ct < 4; ++ct)
#pragma unroll
        for (int tt = 0; tt < 4; ++tt)
          acc[ct][tt] = __builtin_amdgcn_mfma_f32_16x16x32_bf16(afA[ct], bx[tt], acc[ct][tt], 0, 0, 0);
      __builtin_amdgcn_s_setprio(0);
      if (j < 20) {
        const u16* p = wfl + (size_t)(2 * j + 2) * 2048;
#pragma unroll
        for (int ct = 0; ct < 4; ++ct) afA[ct] = *(const bf16x8*)(p + ct * 512);
      }
    }
    // ---- phase B: c = 2j+1 ----
    {
      bf16x8 bx[4];
#pragma unroll
      for (int tt = 0; tt < 4; ++tt)
        bx[tt] = *(const bf16x8*)&xs[(rowbase + tt * 16 + j) * 64 + cid1];
      __builtin_amdgcn_s_setprio(1);
#pragma unroll
      for (int ct = 0; ct < 4; ++ct)
#pragma unroll
        for (int tt = 0; tt < 4; ++tt)
          acc[ct][tt] = __builtin_amdgcn_mfma_f32_16x16x32_bf16(afB[ct], bx[tt], acc[ct][tt], 0, 0, 0);
      __builtin_amdgcn_s_setprio(0);
      if (j < 20) {
        const u16* p = wfl + (size_t)(2 * j + 3) * 2048;
#pragma unroll
        for (int ct = 0; ct < 4; ++ct) afB[ct] = *(const bf16x8*)(p + ct * 512);
      }
    }
  }

  // ---- BN statistics (mask t >= TCn; only tile 63 needs the mask) ----
  const bool full_t = (t0 + TILE <= TCn);
#pragma unroll
  for (int ct = 0; ct < 4; ++ct)
#pragma unroll
    for (int i = 0; i < 4; ++i) {
      float sv = 0.f, sq = 0.f;
      if (full_t) {
#pragma unroll
        for (int tt = 0; tt < 4; ++tt) {
          float v = acc[ct][tt][i];
          sv += v; sq += v * v;
        }
      } else {
#pragma unroll
        for (int tt = 0; tt < 4; ++tt) {
          int tg = t0 + w * 64 + tt * 16 + r;
          if (tg < TCn) {
            float v = acc[ct][tt][i];
            sv += v; sq += v * v;
          }
        }
      }
#pragma unroll
      for (int m = 1; m < 16; m <<= 1) {
        sv += __shfl_xor(sv, m, 64);
        sq += __shfl_xor(sq, m, 64);
      }
      if (r == 0) {
        int co = ct * 16 + q * 4 + i;
        atomicAdd(&sred[co * 2], sv);
        atomicAdd(&sred[co * 2 + 1], sq);
      }
    }

  __syncthreads();   // all waves done reading xs before reuse as y staging

  // ---- store y_t[b][t][co] via LDS transpose (reuse xs), XOR-swizzled ----
  u16* ys = xs;
#pragma unroll
  for (int ct = 0; ct < 4; ++ct)
#pragma unroll
    for (int tt = 0; tt < 4; ++tt) {
      int tl = w * 64 + tt * 16 + r;
      int sw = (tl & 7) * 8;
      int co0 = (ct * 16 + q * 4) ^ sw;        // XOR hits bits 3-5: stays 4-aligned
      u32 lo = (u32)f2bf(acc[ct][tt][0]) | ((u32)f2bf(acc[ct][tt][1]) << 16);
      u32 hi = (u32)f2bf(acc[ct][tt][2]) | ((u32)f2bf(acc[ct][tt][3]) << 16);
      *(uint2*)&ys[tl * 64 + co0] = make_uint2(lo, hi);
    }
  __syncthreads();
  u16* yo = (cv ? y2 : y1) + ((size_t)b * Tn + t0) * 64;
#pragma unroll
  for (int m = 0; m < 8; ++m) {
    int flat = m * 256 + tid;
    int row  = flat >> 3;
    int c0   = (flat & 7) * 8;
    int sw   = (row & 7) * 8;
    *(uint4*)(yo + (size_t)row * 64 + c0) = *(const uint4*)&ys[row * 64 + (c0 ^ sw)];
  }
  if (tid < 128) atomicAdd(&stats[cv * 128 + tid], sred[tid]);
}

// ---------------------------------------------------------------------------
// Kernel 3: SPP, both tensors, vectorized. Block = (b, 1/16th of t).
// Byte-identical to the 483.6 us round-0 version.
// ---------------------------------------------------------------------------
__global__ __launch_bounds__(256) void spp(const u16* __restrict__ y1,
                                           const u16* __restrict__ y2,
                                           const float* __restrict__ stats,
                                           const float* __restrict__ g1v,
                                           const float* __restrict__ b1v,
                                           const float* __restrict__ g2v,
                                           const float* __restrict__ b2v,
                                           const int* __restrict__ orig_len,
                                           u32* __restrict__ featU) {
  const int bx = blockIdx.x;
  const int b  = bx >> 4;
  const int ch = bx & 15;
  const int tid  = threadIdx.x;
  const int g    = tid & 15;       // channel group: co = g*4 .. g*4+3
  const int trow = tid >> 4;       // 0..15
  const int co0  = g * 4;
  const int L     = orig_len[b] - 20;
  const int str2  = L >> 1;
  const int kern2 = L - str2;
  const float Nf = 32.0f * 16364.0f;
  float a1[4], c1[4], a2[4], c2[4];
#pragma unroll
  for (int j = 0; j < 4; ++j) {
    int co = co0 + j;
    float s, sq, mean, var;
    s = stats[co * 2]; sq = stats[co * 2 + 1];
    mean = s / Nf; var = sq / Nf - mean * mean; if (var < 0.f) var = 0.f;
    a1[j] = g1v[co] * rsqrtf(var + 1e-5f);
    c1[j] = b1v[co] - mean * a1[j];
    s = stats[128 + co * 2]; sq = stats[128 + co * 2 + 1];
    mean = s / Nf; var = sq / Nf - mean * mean; if (var < 0.f) var = 0.f;
    a2[j] = g2v[co] * rsqrtf(var + 1e-5f);
    c2[j] = b2v[co] - mean * a2[j];
  }
  float m1[4] = {-3.4e38f,-3.4e38f,-3.4e38f,-3.4e38f};
  float m2[4] = {-3.4e38f,-3.4e38f,-3.4e38f,-3.4e38f};
  float s0[4] = {0,0,0,0}, sb0[4] = {0,0,0,0}, sb1[4] = {0,0,0,0};
  const int tbase = ch * 1024;
  int tend = tbase + 1024;
  if (tend > L) tend = L;
  const u16* p1 = y1 + (size_t)b * Tn * 64 + co0;
  const u16* p2 = y2 + (size_t)b * Tn * 64 + co0;
  for (int t = tbase + trow; t < tend; t += 16) {
    uint2 v1 = *(const uint2*)(p1 + (size_t)t * 64);
    uint2 v2 = *(const uint2*)(p2 + (size_t)t * 64);
    float f1[4] = { bf2f(v1.x & 0xffffu), bf2f(v1.x >> 16),
                    bf2f(v1.y & 0xffffu), bf2f(v1.y >> 16) };
    float f2[4] = { bf2f(v2.x & 0xffffu), bf2f(v2.x >> 16),
                    bf2f(v2.y & 0xffffu), bf2f(v2.y >> 16) };
    bool in0 = (t < kern2), in1 = (t >= str2);   // t < L via tend
#pragma unroll
    for (int j = 0; j < 4; ++j) {
      float z1 = leaky(fmaf(a1[j], f1[j], c1[j]));
      float z2 = leaky(fmaf(a2[j], f2[j], c2[j]));
      s0[j] += z2;
      if (in0) { m1[j] = fmaxf(m1[j], z1); sb0[j] += z2; }
      if (in1) { m2[j] = fmaxf(m2[j], z1); sb1[j] += z2; }
    }
  }
  // reduce across the 4 row-lanes in this wave sharing g (lane>>4)
#pragma unroll
  for (int m = 16; m <= 32; m <<= 1) {
#pragma unroll
    for (int j = 0; j < 4; ++j) {
      m1[j]  = fmaxf(m1[j], __shfl_xor(m1[j], m, 64));
      m2[j]  = fmaxf(m2[j], __shfl_xor(m2[j], m, 64));
      s0[j]  += __shfl_xor(s0[j],  m, 64);
      sb0[j] += __shfl_xor(sb0[j], m, 64);
      sb1[j] += __shfl_xor(sb1[j], m, 64);
    }
  }
  if (((tid & 63) >> 4) == 0) {
    u32* fb = featU + (size_t)b * 384;
    float* ff = (float*)fb;
#pragma unroll
    for (int j = 0; j < 4; ++j) {
      int co = co0 + j;
      u32 e1 = encf(m1[j]), e2 = encf(m2[j]);
      atomicMax(&fb[co], e1 > e2 ? e1 : e2);   // level0 max = max(bin0,bin1)
      atomicMax(&fb[64 + co * 2], e1);
      atomicMax(&fb[64 + co * 2 + 1], e2);
      atomicAdd(&ff[192 + co], s0[j]);
      atomicAdd(&ff[256 + co * 2], sb0[j]);
      atomicAdd(&ff[256 + co * 2 + 1], sb1[j]);
    }
  }
}

// ---------------------------------------------------------------------------
// Kernel 4: FC. feat(32,384) @ fc_w^T(384,2) + fc_b. Round-0 proven version.
// ---------------------------------------------------------------------------
__global__ void fc(const u32* __restrict__ featU,
                   const int* __restrict__ orig_len,
                   const float* __restrict__ fc_w,
                   const float* __restrict__ fc_b,
                   float* __restrict__ out) {
  const int tid  = threadIdx.x;        // 256
  const int pair = tid >> 2;           // (b,n)
  const int part = tid & 3;
  const int b = pair >> 1;
  const int n = pair & 1;
  const int L = orig_len[b] - 20;
  const int kern2 = L - (L >> 1);
  const u32* fb = featU + (size_t)b * 384;
  const float* ff = (const float*)fb;
  float acc = 0.f;
  for (int j = part; j < 384; j += 4) {
    float fv;
    if (j < 192)      fv = decf(fb[j]);
    else if (j < 256) fv = ff[j] / (float)L;
    else              fv = ff[j] / (float)kern2;
    acc += fv * fc_w[n * 384 + j];
  }
  acc += __shfl_xor(acc, 1, 64);
  acc += __shfl_xor(acc, 2, 64);
  if (part == 0) out[b * 2 + n] = acc + fc_b[n];
}

// ---------------------------------------------------------------------------
extern "C" void kernel_launch(void* const* d_in, const int* in_sizes, int n_in,
                              void* d_out, int out_size, void* d_ws, size_t ws_size,
                              hipStream_t stream) {
  const float* x        = (const float*)d_in[0];
  const int*   orig_len = (const int*)d_in[1];
  const float* w1  = (const float*)d_in[2];
  const float* g1  = (const float*)d_in[3];
  const float* b1  = (const float*)d_in[4];
  const float* w2  = (const float*)d_in[5];
  const float* g2  = (const float*)d_in[6];
  const float* b2  = (const float*)d_in[7];
  const float* fcw = (const float*)d_in[8];
  const float* fcb = (const float*)d_in[9];
  float* out = (float*)d_out;

  char* ws = (char*)d_ws;
  const size_t XT_BYTES = (size_t)Bn * TPAD * 64 * 2;    // 67,239,936
  const size_t Y_BYTES  = (size_t)Bn * Tn * 64 * 2;      // 67,108,864
  const size_t WF_BYTES = (size_t)42 * 4 * 64 * 8 * 2;   // 172,032
  size_t off = 0;
  u16* x_t = (u16*)(ws + off); off += XT_BYTES;
  u16* y1  = (u16*)(ws + off); off += Y_BYTES;
  u16* y2  = (u16*)(ws + off); off += Y_BYTES;
  u16* wf1 = (u16*)(ws + off); off += WF_BYTES;
  u16* wf2 = (u16*)(ws + off); off += WF_BYTES;
  float* stats = (float*)(ws + off);                 // 1024 B (2cv x 64co x {s,sq})
  u32*   featU = (u32*)(ws + off + 1024);            // 32*384*4 = 49152 B
  const size_t SMALL_BYTES = 1024 + 49152;

  hipMemsetAsync(ws + off, 0, SMALL_BYTES, stream);
  transpose_x<<<Bn * 256 + 84, 256, 0, stream>>>(x, x_t, w1, w2, wf1, wf2);
  conv_mfma<<<Bn * 64 * 2, 256, 0, stream>>>(x_t, wf1, wf2, y1, y2, stats);
  spp<<<Bn * 16, 256, 0, stream>>>(y1, y2, stats, g1, b1, g2, b2, orig_len, featU);
  fc<<<1, 256, 0, stream>>>(featU, orig_len, fcw, fcb, out);
  (void)in_sizes; (void)n_in; (void)out_size; (void)ws_size;
}

// Round 4
// 395.077 us; speedup vs baseline: 1.4978x; 1.1797x over previous
//
#include <hip/hip_runtime.h>

#define AS1 __attribute__((address_space(1)))
#define AS3 __attribute__((address_space(3)))

using u16 = unsigned short;
using u32 = unsigned int;
typedef __attribute__((ext_vector_type(8))) short bf16x8;
typedef __attribute__((ext_vector_type(4))) float f32x4;

constexpr int Bn    = 32;
constexpr int Tn    = 16384;
constexpr int TCn   = 16364;   // Tn - (K-1)
constexpr int TILE  = 256;     // conv block t-tile (64 tiles exactly)
constexpr int XROWS = 280;     // staged rows per conv block
constexpr int TPAD  = 16416;   // Tn + 32 zero pad rows
constexpr int SPPCH = 64;      // spp chunks per batch row (256 rows each)

__device__ __forceinline__ u16 f2bf(float f) {
  union { float f; u32 u; } v; v.f = f;
  u32 u = v.u;
  u += 0x7fffu + ((u >> 16) & 1u);   // RNE
  return (u16)(u >> 16);
}
__device__ __forceinline__ float bf2f(u32 h) {
  union { u32 u; float f; } v; v.u = h << 16; return v.f;
}
// order-preserving float<->uint (monotone: max(encf a, encf b) = encf(max(a,b)))
__device__ __forceinline__ u32 encf(float f) {
  union { float f; u32 u; } v; v.f = f;
  return (v.u & 0x80000000u) ? ~v.u : (v.u | 0x80000000u);
}
__device__ __forceinline__ float decf(u32 u) {
  union { u32 u; float f; } v;
  v.u = (u & 0x80000000u) ? (u ^ 0x80000000u) : ~u;
  return v.f;
}
__device__ __forceinline__ void gload_lds16(const void* g, void* l) {
  __builtin_amdgcn_global_load_lds((const AS1 u32*)g, (AS3 u32*)l, 16, 0, 0);
}
__device__ __forceinline__ float leaky(float z) { return z > 0.f ? z : 0.01f * z; }

// ---------------------------------------------------------------------------
// Kernel 1: (a) x -> x_t[b][t][ci ^ ((t&7)*8)] bf16 + zero pad; (b) weight
// repack into MFMA A-fragment order. UNCHANGED from the measured rounds.
// ---------------------------------------------------------------------------
__global__ __launch_bounds__(256) void transpose_x(const float* __restrict__ x,
                                                   u16* __restrict__ x_t,
                                                   const float* __restrict__ w1,
                                                   const float* __restrict__ w2,
                                                   u16* __restrict__ wf1,
                                                   u16* __restrict__ wf2) {
  __shared__ u16 lt[64][64];               // 8 KB, [t][ci] (plain)
  const int bx  = blockIdx.x;
  const int tid = threadIdx.x;

  if (bx >= Bn * 256) {                    // ---- weight repack (84 blocks) ----
    const int bxx = bx - Bn * 256;
    const int cv  = bxx / 42;
    const int c   = bxx % 42;
    const float* w = cv ? w2 : w1;
    u16* wf = cv ? wf2 : wf1;
    const int ct   = tid >> 6;
    const int lane = tid & 63;
    const int q  = lane >> 4;
    const int rr = lane & 15;
    const int k  = c >> 1;
    const int cb = (c & 1) * 32;
    const int co = ct * 16 + rr;
    u16 us[8] __attribute__((aligned(16)));
#pragma unroll
    for (int j = 0; j < 8; ++j) {
      int ci = cb + q * 8 + j;
      us[j] = f2bf(w[((size_t)co * 64 + ci) * 21 + k]);
    }
    *(uint4*)&wf[((size_t)(c * 4 + ct) * 64 + lane) * 8] = *(const uint4*)us;
    return;
  }

  const int b   = bx >> 8;
  const int tt  = bx & 255;
  const int t0  = tt * 64;
  const int ci0 = (tid & 15) * 4;
  const int tl0 = (tid >> 4) * 4;
  float4 v[4];
#pragma unroll
  for (int j = 0; j < 4; ++j)
    v[j] = *(const float4*)(x + (size_t)(b * 64 + ci0 + j) * Tn + t0 + tl0);
  float vr[4][4] = {{v[0].x,v[0].y,v[0].z,v[0].w},{v[1].x,v[1].y,v[1].z,v[1].w},
                    {v[2].x,v[2].y,v[2].z,v[2].w},{v[3].x,v[3].y,v[3].z,v[3].w}};
#pragma unroll
  for (int e = 0; e < 4; ++e) {
    int tl = tl0 + e;
    u32 lo = (u32)f2bf(vr[0][e]) | ((u32)f2bf(vr[1][e]) << 16);
    u32 hi = (u32)f2bf(vr[2][e]) | ((u32)f2bf(vr[3][e]) << 16);
    uint2 pk = make_uint2(lo, hi);
    *(uint2*)&lt[tl][ci0] = pk;              // ds_write_b64, PLAIN index
  }
  __syncthreads();
  const int row = tid >> 2;
  const int seg = tid & 3;
  const int c0  = seg * 16;
  const int sw  = (row & 7) * 8;
  u16* op = x_t + ((size_t)b * TPAD + t0 + row) * 64 + c0;
  *(uint4*)op       = *(const uint4*)&lt[row][c0 ^ sw];        // swizzle on READ
  *(uint4*)(op + 8) = *(const uint4*)&lt[row][(c0 + 8) ^ sw];
  if (tt == 0) {
    uint4 z = make_uint4(0u, 0u, 0u, 0u);
    uint4* pz = (uint4*)(x_t + ((size_t)b * TPAD + Tn) * 64);
    pz[tid] = z;
  }
}

// ---------------------------------------------------------------------------
// Kernel 2: implicit-GEMM conv, BARRIER-FREE K-loop. BYTE-IDENTICAL to the
// round-3 measured kernel (173.5 us, MfmaUtil 51%, occ 34%).
// ---------------------------------------------------------------------------
__global__ __launch_bounds__(256, 4) void conv_mfma(const u16* __restrict__ x_t,
                                                    const u16* __restrict__ wf1,
                                                    const u16* __restrict__ wf2,
                                                    u16* __restrict__ y1,
                                                    u16* __restrict__ y2,
                                                    float* __restrict__ stats) {
  __shared__ u16 xs[XROWS * 64];       // 35,840 B
  __shared__ float sred[128];          // 512 B -> total 36,352 B

  const int bid  = blockIdx.x;
  const int cv   = bid & 1;
  const int tmp  = bid >> 1;
  const int tile = tmp & 63;
  const int b    = tmp >> 6;
  const int t0   = tile * TILE;
  const int tid  = threadIdx.x;
  const int w    = tid >> 6;    // wave id
  const int lane = tid & 63;
  const int q    = lane >> 4;
  const int r    = lane & 15;
  const u16* wf  = cv ? wf2 : wf1;

  if (tid < 128) sred[tid] = 0.f;

  // stage x tile: 280 rows * 128B = 35 x 1KB chunks
  const u16* xg = x_t + ((size_t)b * TPAD + t0) * 64;
  for (int s = w; s < 35; s += 4)
    gload_lds16(xg + (size_t)s * 512 + lane * 8, &xs[s * 512]);

  // per-thread weight fragment pointer: frag (c,ct) at wf + c*2048 + ct*512 (+lane*8)
  const u16* wfl = wf + lane * 8;
  bf16x8 afA[4], afB[4];
#pragma unroll
  for (int ct = 0; ct < 4; ++ct) afA[ct] = *(const bf16x8*)(wfl + ct * 512);          // c=0
#pragma unroll
  for (int ct = 0; ct < 4; ++ct) afB[ct] = *(const bf16x8*)(wfl + 2048 + ct * 512);   // c=1

  __syncthreads();   // x tile (and sred init) visible; drains once, before loop

  f32x4 acc[4][4];
#pragma unroll
  for (int a = 0; a < 4; ++a)
#pragma unroll
    for (int t = 0; t < 4; ++t)
      acc[a][t] = (f32x4){0.f, 0.f, 0.f, 0.f};

  const int rowbase = w * 64 + r;

  for (int j = 0; j < 21; ++j) {
    // both phases of pair j share k = j; swizzle line is tt-invariant
    const int swl  = ((rowbase + j) & 7) * 8;
    const int cid0 = (q * 8) ^ swl;          // phase A: cb = 0
    const int cid1 = cid0 ^ 32;              // phase B: cb = 32
    // ---- phase A: c = 2j ----
    {
      bf16x8 bx[4];
#pragma unroll
      for (int tt = 0; tt < 4; ++tt)
        bx[tt] = *(const bf16x8*)&xs[(rowbase + tt * 16 + j) * 64 + cid0];
      __builtin_amdgcn_s_setprio(1);
#pragma unroll
      for (int ct = 0; ct < 4; ++ct)
#pragma unroll
        for (int tt = 0; tt < 4; ++tt)
          acc[ct][tt] = __builtin_amdgcn_mfma_f32_16x16x32_bf16(afA[ct], bx[tt], acc[ct][tt], 0, 0, 0);
      __builtin_amdgcn_s_setprio(0);
      if (j < 20) {
        const u16* p = wfl + (size_t)(2 * j + 2) * 2048;
#pragma unroll
        for (int ct = 0; ct < 4; ++ct) afA[ct] = *(const bf16x8*)(p + ct * 512);
      }
    }
    // ---- phase B: c = 2j+1 ----
    {
      bf16x8 bx[4];
#pragma unroll
      for (int tt = 0; tt < 4; ++tt)
        bx[tt] = *(const bf16x8*)&xs[(rowbase + tt * 16 + j) * 64 + cid1];
      __builtin_amdgcn_s_setprio(1);
#pragma unroll
      for (int ct = 0; ct < 4; ++ct)
#pragma unroll
        for (int tt = 0; tt < 4; ++tt)
          acc[ct][tt] = __builtin_amdgcn_mfma_f32_16x16x32_bf16(afB[ct], bx[tt], acc[ct][tt], 0, 0, 0);
      __builtin_amdgcn_s_setprio(0);
      if (j < 20) {
        const u16* p = wfl + (size_t)(2 * j + 3) * 2048;
#pragma unroll
        for (int ct = 0; ct < 4; ++ct) afB[ct] = *(const bf16x8*)(p + ct * 512);
      }
    }
  }

  // ---- BN statistics (mask t >= TCn; only tile 63 needs the mask) ----
  const bool full_t = (t0 + TILE <= TCn);
#pragma unroll
  for (int ct = 0; ct < 4; ++ct)
#pragma unroll
    for (int i = 0; i < 4; ++i) {
      float sv = 0.f, sq = 0.f;
      if (full_t) {
#pragma unroll
        for (int tt = 0; tt < 4; ++tt) {
          float v = acc[ct][tt][i];
          sv += v; sq += v * v;
        }
      } else {
#pragma unroll
        for (int tt = 0; tt < 4; ++tt) {
          int tg = t0 + w * 64 + tt * 16 + r;
          if (tg < TCn) {
            float v = acc[ct][tt][i];
            sv += v; sq += v * v;
          }
        }
      }
#pragma unroll
      for (int m = 1; m < 16; m <<= 1) {
        sv += __shfl_xor(sv, m, 64);
        sq += __shfl_xor(sq, m, 64);
      }
      if (r == 0) {
        int co = ct * 16 + q * 4 + i;
        atomicAdd(&sred[co * 2], sv);
        atomicAdd(&sred[co * 2 + 1], sq);
      }
    }

  __syncthreads();   // all waves done reading xs before reuse as y staging

  // ---- store y_t[b][t][co] via LDS transpose (reuse xs), XOR-swizzled ----
  u16* ys = xs;
#pragma unroll
  for (int ct = 0; ct < 4; ++ct)
#pragma unroll
    for (int tt = 0; tt < 4; ++tt) {
      int tl = w * 64 + tt * 16 + r;
      int sw = (tl & 7) * 8;
      int co0 = (ct * 16 + q * 4) ^ sw;        // XOR hits bits 3-5: stays 4-aligned
      u32 lo = (u32)f2bf(acc[ct][tt][0]) | ((u32)f2bf(acc[ct][tt][1]) << 16);
      u32 hi = (u32)f2bf(acc[ct][tt][2]) | ((u32)f2bf(acc[ct][tt][3]) << 16);
      *(uint2*)&ys[tl * 64 + co0] = make_uint2(lo, hi);
    }
  __syncthreads();
  u16* yo = (cv ? y2 : y1) + ((size_t)b * Tn + t0) * 64;
#pragma unroll
  for (int m = 0; m < 8; ++m) {
    int flat = m * 256 + tid;
    int row  = flat >> 3;
    int c0   = (flat & 7) * 8;
    int sw   = (row & 7) * 8;
    *(uint4*)(yo + (size_t)row * 64 + c0) = *(const uint4*)&ys[row * 64 + (c0 ^ sw)];
  }
  if (tid < 128) atomicAdd(&stats[cv * 128 + tid], sred[tid]);
}

// ---------------------------------------------------------------------------
// Kernel 3: SPP — ATOMIC-FREE. Grid = 32b x 64 chunks of 256 rows (2048
// blocks, 8/CU). Wave shuffle-reduce (proven) -> cross-wave LDS combine ->
// each block writes its 384-slot partial (maxes encf-encoded u32, sums f32)
// to part[block][384]. No global atomics (round-0 had 786K contended atomics;
// round-1's 3.1M explains its +78us). fc reduces the partials.
// ---------------------------------------------------------------------------
__global__ __launch_bounds__(256) void spp(const u16* __restrict__ y1,
                                           const u16* __restrict__ y2,
                                           const float* __restrict__ stats,
                                           const float* __restrict__ g1v,
                                           const float* __restrict__ b1v,
                                           const float* __restrict__ g2v,
                                           const float* __restrict__ b2v,
                                           const int* __restrict__ orig_len,
                                           u32* __restrict__ part) {
  __shared__ float lred[4][16][4][5];    // 5 KB: [wave][g][j][{m1,m2,s0,sb0,sb1}]
  const int bx = blockIdx.x;
  const int b  = bx >> 6;
  const int ch = bx & 63;
  const int tid  = threadIdx.x;
  const int g    = tid & 15;       // channel group: co = g*4 .. g*4+3
  const int trow = tid >> 4;       // 0..15 (spans waves)
  const int wv   = tid >> 6;       // wave id
  const int co0  = g * 4;
  const int L     = orig_len[b] - 20;
  const int str2  = L >> 1;
  const int kern2 = L - str2;
  const float Nf = 32.0f * 16364.0f;
  float a1[4], c1[4], a2[4], c2[4];
#pragma unroll
  for (int j = 0; j < 4; ++j) {
    int co = co0 + j;
    float s, sq, mean, var;
    s = stats[co * 2]; sq = stats[co * 2 + 1];
    mean = s / Nf; var = sq / Nf - mean * mean; if (var < 0.f) var = 0.f;
    a1[j] = g1v[co] * rsqrtf(var + 1e-5f);
    c1[j] = b1v[co] - mean * a1[j];
    s = stats[128 + co * 2]; sq = stats[128 + co * 2 + 1];
    mean = s / Nf; var = sq / Nf - mean * mean; if (var < 0.f) var = 0.f;
    a2[j] = g2v[co] * rsqrtf(var + 1e-5f);
    c2[j] = b2v[co] - mean * a2[j];
  }
  float m1[4] = {-3.4e38f,-3.4e38f,-3.4e38f,-3.4e38f};
  float m2[4] = {-3.4e38f,-3.4e38f,-3.4e38f,-3.4e38f};
  float s0[4] = {0,0,0,0}, sb0[4] = {0,0,0,0}, sb1[4] = {0,0,0,0};
  const int tbase = ch * 256;
  int tend = tbase + 256;
  if (tend > L) tend = L;
  const u16* p1 = y1 + (size_t)b * Tn * 64 + co0;
  const u16* p2 = y2 + (size_t)b * Tn * 64 + co0;

  auto body = [&](int t) {
    uint2 v1 = *(const uint2*)(p1 + (size_t)t * 64);
    uint2 v2 = *(const uint2*)(p2 + (size_t)t * 64);
    float f1[4] = { bf2f(v1.x & 0xffffu), bf2f(v1.x >> 16),
                    bf2f(v1.y & 0xffffu), bf2f(v1.y >> 16) };
    float f2[4] = { bf2f(v2.x & 0xffffu), bf2f(v2.x >> 16),
                    bf2f(v2.y & 0xffffu), bf2f(v2.y >> 16) };
    bool in0 = (t < kern2), in1 = (t >= str2);   // t < L via tend
#pragma unroll
    for (int j = 0; j < 4; ++j) {
      float z1 = leaky(fmaf(a1[j], f1[j], c1[j]));
      float z2 = leaky(fmaf(a2[j], f2[j], c2[j]));
      s0[j] += z2;
      if (in0) { m1[j] = fmaxf(m1[j], z1); sb0[j] += z2; }
      if (in1) { m2[j] = fmaxf(m2[j], z1); sb1[j] += z2; }
    }
  };

  if (tend == tbase + 256) {
    // full chunk: exactly 16 iterations
#pragma unroll 4
    for (int it = 0; it < 16; ++it)
      body(tbase + trow + it * 16);
  } else {
    for (int t = tbase + trow; t < tend; t += 16)
      body(t);
  }

  // reduce across the 4 row-lanes in this wave sharing g (lane>>4)
#pragma unroll
  for (int m = 16; m <= 32; m <<= 1) {
#pragma unroll
    for (int j = 0; j < 4; ++j) {
      m1[j]  = fmaxf(m1[j], __shfl_xor(m1[j], m, 64));
      m2[j]  = fmaxf(m2[j], __shfl_xor(m2[j], m, 64));
      s0[j]  += __shfl_xor(s0[j],  m, 64);
      sb0[j] += __shfl_xor(sb0[j], m, 64);
      sb1[j] += __shfl_xor(sb1[j], m, 64);
    }
  }
  if (((tid & 63) >> 4) == 0) {          // lanes 0-15 of each wave
#pragma unroll
    for (int j = 0; j < 4; ++j) {
      lred[wv][g][j][0] = m1[j];
      lred[wv][g][j][1] = m2[j];
      lred[wv][g][j][2] = s0[j];
      lred[wv][g][j][3] = sb0[j];
      lred[wv][g][j][4] = sb1[j];
    }
  }
  __syncthreads();
  if (tid < 64) {                        // one thread per co
    const int co = tid;
    const int g2 = co >> 2, j2 = co & 3;
    float fm1 = lred[0][g2][j2][0], fm2 = lred[0][g2][j2][1];
    float fs0 = lred[0][g2][j2][2], fb0 = lred[0][g2][j2][3], fb1v_ = lred[0][g2][j2][4];
#pragma unroll
    for (int k = 1; k < 4; ++k) {
      fm1 = fmaxf(fm1, lred[k][g2][j2][0]);
      fm2 = fmaxf(fm2, lred[k][g2][j2][1]);
      fs0 += lred[k][g2][j2][2];
      fb0 += lred[k][g2][j2][3];
      fb1v_ += lred[k][g2][j2][4];
    }
    u32* pp = part + (size_t)bx * 384;
    float* pf = (float*)pp;
    u32 e1 = encf(fm1), e2 = encf(fm2);
    pp[co]              = e1 > e2 ? e1 : e2;   // level0 max = max(bin0,bin1)
    pp[64 + co * 2]     = e1;
    pp[64 + co * 2 + 1] = e2;
    pf[192 + co]         = fs0;
    pf[256 + co * 2]     = fb0;
    pf[256 + co * 2 + 1] = fb1v_;
  }
}

// ---------------------------------------------------------------------------
// Kernel 4: FC + partial reduction. 32 blocks (one per b) x 384 threads.
// Thread j reduces feature j over the 64 chunk-partials (coalesced 1536 B per
// iteration), decodes/scales, multiplies by fc_w, then shuffle+LDS reduce.
// ---------------------------------------------------------------------------
__global__ __launch_bounds__(384) void fc(const u32* __restrict__ part,
                                          const int* __restrict__ orig_len,
                                          const float* __restrict__ fc_w,
                                          const float* __restrict__ fc_b,
                                          float* __restrict__ out) {
  __shared__ float r0s[6], r1s[6];
  const int b = blockIdx.x;
  const int j = threadIdx.x;           // 0..383
  const int L = orig_len[b] - 20;
  const int kern2 = L - (L >> 1);
  const u32* pb = part + (size_t)b * 64 * 384;
  float fv;
  if (j < 192) {
    u32 vmax = 0u;
    for (int c = 0; c < 64; ++c) {
      u32 v = pb[(size_t)c * 384 + j];
      vmax = v > vmax ? v : vmax;
    }
    fv = decf(vmax);
  } else {
    const float* pf = (const float*)pb;
    float s = 0.f;
    for (int c = 0; c < 64; ++c) s += pf[(size_t)c * 384 + j];
    fv = (j < 256) ? s / (float)L : s / (float)kern2;
  }
  float a0 = fv * fc_w[j];
  float a1 = fv * fc_w[384 + j];
#pragma unroll
  for (int m = 1; m < 64; m <<= 1) {
    a0 += __shfl_xor(a0, m, 64);
    a1 += __shfl_xor(a1, m, 64);
  }
  const int wv = j >> 6, ln = j & 63;
  if (ln == 0) { r0s[wv] = a0; r1s[wv] = a1; }
  __syncthreads();
  if (j == 0) {
    float t0 = 0.f, t1 = 0.f;
#pragma unroll
    for (int k = 0; k < 6; ++k) { t0 += r0s[k]; t1 += r1s[k]; }
    out[b * 2]     = t0 + fc_b[0];
    out[b * 2 + 1] = t1 + fc_b[1];
  }
}

// ---------------------------------------------------------------------------
extern "C" void kernel_launch(void* const* d_in, const int* in_sizes, int n_in,
                              void* d_out, int out_size, void* d_ws, size_t ws_size,
                              hipStream_t stream) {
  const float* x        = (const float*)d_in[0];
  const int*   orig_len = (const int*)d_in[1];
  const float* w1  = (const float*)d_in[2];
  const float* g1  = (const float*)d_in[3];
  const float* b1  = (const float*)d_in[4];
  const float* w2  = (const float*)d_in[5];
  const float* g2  = (const float*)d_in[6];
  const float* b2  = (const float*)d_in[7];
  const float* fcw = (const float*)d_in[8];
  const float* fcb = (const float*)d_in[9];
  float* out = (float*)d_out;

  char* ws = (char*)d_ws;
  const size_t XT_BYTES = (size_t)Bn * TPAD * 64 * 2;    // 67,239,936
  const size_t Y_BYTES  = (size_t)Bn * Tn * 64 * 2;      // 67,108,864
  const size_t WF_BYTES = (size_t)42 * 4 * 64 * 8 * 2;   // 172,032
  size_t off = 0;
  u16* x_t = (u16*)(ws + off); off += XT_BYTES;
  u16* y1  = (u16*)(ws + off); off += Y_BYTES;
  u16* y2  = (u16*)(ws + off); off += Y_BYTES;
  u16* wf1 = (u16*)(ws + off); off += WF_BYTES;
  u16* wf2 = (u16*)(ws + off); off += WF_BYTES;
  float* stats = (float*)(ws + off);                 // 1024 B (2cv x 64co x {s,sq})
  u32*   part  = (u32*)(ws + off + 1024);            // 2048 * 384 * 4 = 3,145,728 B

  hipMemsetAsync(stats, 0, 1024, stream);            // partials need no memset
  transpose_x<<<Bn * 256 + 84, 256, 0, stream>>>(x, x_t, w1, w2, wf1, wf2);
  conv_mfma<<<Bn * 64 * 2, 256, 0, stream>>>(x_t, wf1, wf2, y1, y2, stats);
  spp<<<Bn * SPPCH, 256, 0, stream>>>(y1, y2, stats, g1, b1, g2, b2, orig_len, part);
  fc<<<Bn, 384, 0, stream>>>(part, orig_len, fcw, fcb, out);
  (void)in_sizes; (void)n_in; (void)out_size; (void)ws_size;
}